// Round 11
// baseline (299.404 us; speedup 1.0000x reference)
//
#include <hip/hip_runtime.h>
#include <hip/hip_bf16.h>
#include <stdint.h>

// Problem constants: B=4, S=2048, D=1024, H=16, Dh=64
#define LOG2E 1.44269504088896340736f
#define SCL   (0.125f * LOG2E)   // folded into Q at the gemm epilogue

typedef __attribute__((ext_vector_type(8)))  short short8;     // 8 bf16 (4 VGPRs)
typedef __attribute__((ext_vector_type(16))) float floatx16;   // 32x32 C/D frag
typedef __attribute__((ext_vector_type(4)))  unsigned short ushort4v;

// global -> LDS direct DMA, 16B/lane (gemm staging only).
#define GLP(g, l)                                                              \
    __builtin_amdgcn_global_load_lds(                                          \
        (const __attribute__((address_space(1))) void*)(g),                    \
        (__attribute__((address_space(3))) void*)(l), 16, 0, 0)

#if __has_builtin(__builtin_amdgcn_exp2f)
#define EXP2(x) __builtin_amdgcn_exp2f(x)   // raw v_exp_f32 (args bounded here)
#else
#define EXP2(x) exp2f(x)
#endif

static __device__ __forceinline__ unsigned short f2bf(float f) {
    union { float f; unsigned u; } v; v.f = f;
    unsigned r = v.u + 0x7FFFu + ((v.u >> 16) & 1u);  // RNE
    return (unsigned short)(r >> 16);
}

static __device__ __forceinline__ unsigned pack2bf(float a, float b) {
    __hip_bfloat162 h = __float22bfloat162_rn(make_float2(a, b));
    union { __hip_bfloat162 h; unsigned u; } c; c.h = h; return c.u;
}

// ------- merged fp32->bf16 convert: X | Wq|Wk|Wv | mask(xLOG2E) in one launch -------
__global__ __launch_bounds__(256) void cvt_all(const float* __restrict__ X,
                                               const float* __restrict__ Wq,
                                               const float* __restrict__ Wk,
                                               const float* __restrict__ Wv,
                                               const float* __restrict__ mask,
                                               unsigned short* __restrict__ xb,
                                               unsigned short* __restrict__ wb,
                                               float* __restrict__ maskl) {
    int i = blockIdx.x * 256 + threadIdx.x;   // 2097152 X + 786432 W + 2048 mask float4s
    if (i < 2097152) {
        float4 v = ((const float4*)X)[i];
        ushort4v o;
        o.x = f2bf(v.x); o.y = f2bf(v.y); o.z = f2bf(v.z); o.w = f2bf(v.w);
        ((ushort4v*)xb)[i] = o;
    } else if (i < 2883584) {
        int j = i - 2097152;
        const float* src; int k;
        if (j < 262144)      { src = Wq; k = j; }
        else if (j < 524288) { src = Wk; k = j - 262144; }
        else                 { src = Wv; k = j - 524288; }
        float4 v = ((const float4*)src)[k];
        ushort4v o;
        o.x = f2bf(v.x); o.y = f2bf(v.y); o.z = f2bf(v.z); o.w = f2bf(v.w);
        ((ushort4v*)wb)[j] = o;
    } else if (i < 2883584 + 2048) {
        int j = i - 2883584;
        float4 v = ((const float4*)mask)[j];
        ((float4*)maskl)[j] = make_float4(v.x * LOG2E, v.y * LOG2E,
                                          v.z * LOG2E, v.w * LOG2E);
    }
}

// ---------------- fused QKV projection GEMM (32x32x16 MFMA) ----------------
// C[m][n] = sum_k X[m][k] * W[n][k] + bias[n]   (NT gemm)
// Q scaled by SCL, row-major [8192][1024].
// K in MFMA-FRAG layout per head (131072 el): unit (key,d-chunk c=d>>3) at
//   (key>>5)*2048 + c*256 + (key&31)*8   -> attn aK load = coalesced 1KB/wave.
// V^T in frag layout per head, key PERMUTED (bit2<->bit3 of key, matching P's
//   natural A-frag order): (sp>>7)*8192 + (d>>5)*4096 + ((sp>>3)&15)*256
//   + (d&31)*8 + (sp&7)   -> attn bV load = coalesced 1KB/wave.
__global__ __launch_bounds__(256) void qkv_gemm(
        const unsigned short* __restrict__ X,   // [8192][1024] bf16
        const unsigned short* __restrict__ W,   // [3072][1024] bf16
        const float* __restrict__ bq, const float* __restrict__ bk,
        const float* __restrict__ bv,
        unsigned short* __restrict__ Qf,        // [8192][1024]  (pre-scaled by SCL)
        unsigned short* __restrict__ Kg,        // frag layout, 64 heads x 131072
        unsigned short* __restrict__ Vg)        // frag layout, key-permuted
{
    __shared__ __align__(16) unsigned short sh[17408];  // A(8192) B(8192); C-tile 128x136
    unsigned short* Ash = sh;
    unsigned short* Bsh = sh + 8192;

    const int tid  = threadIdx.x;
    const int lane = tid & 63;
    const int wv   = tid >> 6;
    const int q32  = lane & 31;
    const int hi   = lane >> 5;
    const int mBase = blockIdx.x * 128;
    const int nBase = blockIdx.y * 128;
    const int wm = (wv >> 1) * 64;
    const int wn = (wv & 1) * 64;

    floatx16 acc[2][2];
    acc[0][0] = 0.0f; acc[0][1] = 0.0f; acc[1][0] = 0.0f; acc[1][1] = 0.0f;

    const int sr = lane >> 3;            // 0..7 row-in-group
    const int kc = (lane & 7) ^ sr;      // swizzled 16B chunk

    for (int kb = 0; kb < 1024; kb += 64) {
        __syncthreads();
#pragma unroll
        for (int s = 0; s < 4; ++s) {
            const int seg = wv * 4 + s;          // row-group 0..15 (8 rows each)
            const int row = seg * 8 + sr;
            GLP(X + (size_t)(mBase + row) * 1024 + kb + kc * 8, Ash + seg * 512);
            GLP(W + (size_t)(nBase + row) * 1024 + kb + kc * 8, Bsh + seg * 512);
        }
        __syncthreads();
#pragma unroll
        for (int ks = 0; ks < 4; ++ks) {         // K=16 steps within BK=64
            short8 aF[2], bF[2];
#pragma unroll
            for (int mi = 0; mi < 2; ++mi) {
                const int R = wm + mi * 32 + q32;
                const int slot = (2 * ks + hi) ^ (R & 7);
                aF[mi] = *(const short8*)(Ash + (R >> 3) * 512 + (R & 7) * 64 + slot * 8);
            }
#pragma unroll
            for (int ni = 0; ni < 2; ++ni) {
                const int R = wn + ni * 32 + q32;
                const int slot = (2 * ks + hi) ^ (R & 7);
                bF[ni] = *(const short8*)(Bsh + (R >> 3) * 512 + (R & 7) * 64 + slot * 8);
            }
#pragma unroll
            for (int mi = 0; mi < 2; ++mi)
#pragma unroll
                for (int ni = 0; ni < 2; ++ni)
                    acc[mi][ni] = __builtin_amdgcn_mfma_f32_32x32x16_bf16(
                        aF[mi], bF[ni], acc[mi][ni], 0, 0, 0);
        }
    }

    // 32x32 C/D layout: col = lane&31, row = (r&3) + 8*(r>>2) + 4*hi (+ mi*32)
    if (blockIdx.y < 16) {
        // ---- Q or K: LDS transpose; Q -> row-major, K -> frag layout ----
        const bool isQ = (blockIdx.y < 8);
        const float* bias = isQ ? bq : bk;
        const float scl   = isQ ? SCL : 1.0f;
        const int nb = nBase & 1023;
        float bj[2];
#pragma unroll
        for (int ni = 0; ni < 2; ++ni)
            bj[ni] = bias[nb + wn + ni * 32 + q32];
        __syncthreads();   // A/B LDS now dead for all waves
#pragma unroll
        for (int ni = 0; ni < 2; ++ni) {
            const int col = wn + ni * 32 + q32;
#pragma unroll
            for (int mi = 0; mi < 2; ++mi)
#pragma unroll
                for (int g = 0; g < 4; ++g) {
                    const int row0 = wm + mi * 32 + g * 8 + hi * 4;
#pragma unroll
                    for (int rr = 0; rr < 4; ++rr)
                        sh[(row0 + rr) * 136 + col] =
                            f2bf((acc[mi][ni][g * 4 + rr] + bj[ni]) * scl);
                }
        }
        __syncthreads();
        if (isQ) {
#pragma unroll
            for (int it = 0; it < 8; ++it) {
                const int row  = it * 16 + (tid >> 4);
                const int part = tid & 15;
                short8 v = *(const short8*)(sh + row * 136 + part * 8);
                *(short8*)(Qf + (size_t)(mBase + row) * 1024 + nb + part * 8) = v;
            }
        } else {
            const int b0 = mBase >> 11;
            const int sB = mBase & 2047;
#pragma unroll
            for (int it = 0; it < 8; ++it) {
                const int row = it * 16 + (tid >> 4);
                const int p   = tid & 15;
                short8 v = *(const short8*)(sh + row * 136 + p * 8);
                const int head = (nb >> 6) + (p >> 3);
                const int s    = sB + row;
                *(short8*)(Kg + (size_t)(b0 * 16 + head) * 131072
                              + (s >> 5) * 2048 + (p & 7) * 256 + (s & 31) * 8) = v;
            }
        }
    } else {
        // ---- V: frag-layout stores, key bits 2<->3 swapped ----
#pragma unroll
        for (int ni = 0; ni < 2; ++ni) {
            const int gn = nBase + wn + ni * 32 + q32;     // 2048..3071
            const int c  = gn & 1023;
            const int h  = c >> 6;
            const int d  = c & 63;
            const float bias = bv[c];
#pragma unroll
            for (int mi = 0; mi < 2; ++mi)
#pragma unroll
                for (int g = 0; g < 4; ++g) {
                    const int m0 = mBase + wm + mi * 32 + g * 8 + hi * 4;
                    const int b  = m0 >> 11;
                    const int s0 = m0 & 2047;
                    const int sp = (s0 & ~12) | ((s0 & 4) << 1) | ((s0 & 8) >> 1);
                    ushort4v pv;
#pragma unroll
                    for (int rr = 0; rr < 4; ++rr)
                        pv[rr] = f2bf(acc[mi][ni][g * 4 + rr] + bias);
                    *(ushort4v*)(Vg + (size_t)(b * 16 + h) * 131072
                                    + (sp >> 7) * 8192 + (d >> 5) * 4096
                                    + ((sp >> 3) & 15) * 256 + (d & 31) * 8
                                    + (sp & 7)) = pv;
                }
        }
    }
}

// -------- flash attention: barrier-free, frag-layout K/V, zero-exchange P --------
// NO LDS staging, NO __syncthreads in the K-loop: every aK/bV read is one
// coalesced 1KB global_load_dwordx4 from the frag layout (L1/L2-served; all 4
// waves of a block read identical K/V lines). Compiler is free to pipeline
// loads across MFMAs with fine-grained vmcnt — the thing the 2-barrier
// structure could not express. Math identical to round 10 (same Vt permutation,
// mask as S-MFMA C-init, l in C-layout VALU, natural-order P packing).
__global__ __launch_bounds__(256, 4) void attn_kernel(
        const unsigned short* __restrict__ Qf,   // [8192][1024] bf16 (x SCL)
        const unsigned short* __restrict__ Kg,   // frag layout per head
        const unsigned short* __restrict__ Vg,   // frag layout per head, key-permuted
        const float* __restrict__ maskl,         // [4][2048], pre-scaled by LOG2E
        float* __restrict__ out)                 // [4][2048][1024]
{
    __shared__ __align__(16) float Lsh[128];     // per-wave 1/l(q), end only

    const int tid  = threadIdx.x;
    const int lane = tid & 63;
    const int wv   = tid >> 6;
    const int q32  = lane & 31;
    const int hi   = lane >> 5;
    const int bh   = blockIdx.x & 63;
    const int qt   = blockIdx.x >> 6;
    const int b    = bh >> 4;
    const int h    = bh & 15;
    const int q0   = qt * 128 + wv * 32;

    // Q as B-operand fragments (row=q=lane&31, k=8*hi+j), loaded once
    short8 bQ[4];
#pragma unroll
    for (int ks = 0; ks < 4; ++ks)
        bQ[ks] = *(const short8*)(Qf + (size_t)(b * 2048 + q0 + q32) * 1024
                                     + h * 64 + ks * 16 + hi * 8);

    floatx16 accO0 = 0.0f, accO1 = 0.0f;
    float l_c = 0.0f;

    const unsigned short* pK = Kg + (size_t)bh * 131072 + hi * 256 + q32 * 8;
    const unsigned short* pV = Vg + (size_t)bh * 131072 + hi * 256 + q32 * 8;
    const float*          pM = maskl + b * 2048 + hi * 4;

    for (int kb = 0; kb < 2048; kb += 128) {
#pragma unroll
        for (int half = 0; half < 2; ++half) {
#pragma unroll
            for (int mt = 0; mt < 2; ++mt) {
                // S^T tile: A = K (m=key 32), B = Q' (n=query 32), C init = mask
                floatx16 sacc;
#pragma unroll
                for (int a = 0; a < 4; ++a) {
                    float4 mv4 = *(const float4*)(pM + half * 64 + mt * 32 + a * 8);
                    sacc[a * 4 + 0] = mv4.x; sacc[a * 4 + 1] = mv4.y;
                    sacc[a * 4 + 2] = mv4.z; sacc[a * 4 + 3] = mv4.w;
                }
#pragma unroll
                for (int ks = 0; ks < 4; ++ks) {
                    short8 aK = *(const short8*)(pK + half * 4096 + mt * 2048 + ks * 512);
                    sacc = __builtin_amdgcn_mfma_f32_32x32x16_bf16(aK, bQ[ks], sacc, 0, 0, 0);
                }
                // p = exp2(sacc); pack in NATURAL reg order (V keys pre-permuted)
                unsigned u[8];
#pragma unroll
                for (int a = 0; a < 4; ++a) {
                    float p0 = EXP2(sacc[a * 4 + 0]);
                    float p1 = EXP2(sacc[a * 4 + 1]);
                    float p2 = EXP2(sacc[a * 4 + 2]);
                    float p3 = EXP2(sacc[a * 4 + 3]);
                    l_c += (p0 + p1) + (p2 + p3);
                    u[2 * a]     = pack2bf(p0, p1);
                    u[2 * a + 1] = pack2bf(p2, p3);
                }
#pragma unroll
                for (int ks2 = 0; ks2 < 2; ++ks2) {
                    union { unsigned uu[4]; short8 s; } aP;
                    aP.uu[0] = u[4 * ks2 + 0];
                    aP.uu[1] = u[4 * ks2 + 1];
                    aP.uu[2] = u[4 * ks2 + 2];
                    aP.uu[3] = u[4 * ks2 + 3];
                    short8 bV0 = *(const short8*)(pV + half * 2048 + mt * 1024 + ks2 * 512);
                    short8 bV1 = *(const short8*)(pV + 4096 + half * 2048 + mt * 1024 + ks2 * 512);
                    accO0 = __builtin_amdgcn_mfma_f32_32x32x16_bf16(aP.s, bV0, accO0, 0, 0, 0);
                    accO1 = __builtin_amdgcn_mfma_f32_32x32x16_bf16(aP.s, bV1, accO1, 0, 0, 0);
                }
            }
        }
        pK += 8192;
        pV += 8192;
        pM += 128;
    }

    // l(q): combine the two hi-halves, redistribute to row-indexed layout via Lsh
    l_c += __shfl_xor(l_c, 32, 64);
    if (lane < 32) Lsh[wv * 32 + q32] = 1.0f / l_c;
    // wave-synchronous: same wave wrote Lsh; compiler orders via lgkmcnt
#pragma unroll
    for (int g = 0; g < 4; ++g) {
        float4 inv4 = *(const float4*)(Lsh + wv * 32 + g * 8 + hi * 4);
#pragma unroll
        for (int rr = 0; rr < 4; ++rr) {
            const int r   = g * 4 + rr;
            const int row = rr + 8 * g + 4 * hi;
            const float linv = (rr == 0) ? inv4.x : (rr == 1) ? inv4.y
                             : (rr == 2) ? inv4.z : inv4.w;
            float* op = out + (size_t)(b * 2048 + q0 + row) * 1024 + h * 64 + q32;
            op[0]  = accO0[r] * linv;
            op[32] = accO1[r] * linv;
        }
    }
}

// ---------------- launch ----------------
extern "C" void kernel_launch(void* const* d_in, const int* in_sizes, int n_in,
                              void* d_out, int out_size, void* d_ws, size_t ws_size,
                              hipStream_t stream) {
    const float* X    = (const float*)d_in[0];
    const float* mask = (const float*)d_in[1];
    const float* Wq   = (const float*)d_in[2];
    const float* bq   = (const float*)d_in[3];
    const float* Wk   = (const float*)d_in[4];
    const float* bk   = (const float*)d_in[5];
    const float* Wv   = (const float*)d_in[6];
    const float* bv   = (const float*)d_in[7];
    float* out = (float*)d_out;

    char* ws = (char*)d_ws;
    unsigned short* xb  = (unsigned short*)(ws);                // 8192*1024 bf16 (16MB)
    unsigned short* wb  = (unsigned short*)(ws + 16777216);     // 3072*1024 bf16 (6MB)
    unsigned short* qf  = (unsigned short*)(ws + 23068672);     // [8192][1024] (16MB)
    unsigned short* kg  = (unsigned short*)(ws + 39845888);     // K frag (16MB)
    unsigned short* vg  = (unsigned short*)(ws + 56623104);     // V frag (16MB)
    float*          ml  = (float*)(ws + 73400320);              // [4][2048] (32KB)

    cvt_all<<<11272, 256, 0, stream>>>(X, Wq, Wk, Wv, mask, xb, wb, ml);

    qkv_gemm<<<dim3(64, 24), 256, 0, stream>>>(xb, wb, bq, bk, bv, qf, kg, vg);

    attn_kernel<<<1024, 256, 0, stream>>>(qf, kg, vg, ml, out);
}